// Round 2
// baseline (981.478 us; speedup 1.0000x reference)
//
#include <hip/hip_runtime.h>
#include <hip/hip_bf16.h>
#include <math.h>

#define N_TOKENS 8192
#define DIM 7168
#define NEXP 256

// ---------------- GEMM: L[8192][256] = X[8192][7168] @ W[7168][256] (f32) ----------------
constexpr int BM = 64, BN = 64, BK = 32;

__global__ __launch_bounds__(256) void gemm_f32(const float* __restrict__ X,
                                                const float* __restrict__ W,
                                                float* __restrict__ L) {
  __shared__ float xs[BK][BM + 8];  // transposed: xs[k][m], row stride 72 floats (16B aligned)
  __shared__ float ws[BK][BN + 8];
  const int bm = blockIdx.x * BM;
  const int bn = blockIdx.y * BN;
  const int t = threadIdx.x;
  const int tm = (t & 15) * 4;
  const int tn = (t >> 4) * 4;
  float acc[4][4] = {};
  for (int k0 = 0; k0 < DIM; k0 += BK) {
    // load X tile (64 rows x 32 k), store transposed
#pragma unroll
    for (int r = 0; r < 2; ++r) {
      int i = t + 256 * r;
      int row = i >> 3, kq = (i & 7) * 4;
      float4 v = *reinterpret_cast<const float4*>(X + (size_t)(bm + row) * DIM + k0 + kq);
      xs[kq + 0][row] = v.x;
      xs[kq + 1][row] = v.y;
      xs[kq + 2][row] = v.z;
      xs[kq + 3][row] = v.w;
    }
    // load W tile (32 k x 64 n)
#pragma unroll
    for (int r = 0; r < 2; ++r) {
      int i = t + 256 * r;
      int kk = i >> 4, nq = (i & 15) * 4;
      float4 v = *reinterpret_cast<const float4*>(W + (size_t)(k0 + kk) * NEXP + bn + nq);
      *reinterpret_cast<float4*>(&ws[kk][nq]) = v;
    }
    __syncthreads();
    // per-tile sub-accumulator (keeps rounding error ~sqrt(n_tiles) instead of sqrt(K))
    float sub[4][4] = {};
#pragma unroll
    for (int kk = 0; kk < BK; ++kk) {
      float4 a = *reinterpret_cast<const float4*>(&xs[kk][tm]);
      float4 b = *reinterpret_cast<const float4*>(&ws[kk][tn]);
      float av[4] = {a.x, a.y, a.z, a.w};
      float bv[4] = {b.x, b.y, b.z, b.w};
#pragma unroll
      for (int i = 0; i < 4; ++i)
#pragma unroll
        for (int j = 0; j < 4; ++j) sub[i][j] = fmaf(av[i], bv[j], sub[i][j]);
    }
#pragma unroll
    for (int i = 0; i < 4; ++i)
#pragma unroll
      for (int j = 0; j < 4; ++j) acc[i][j] += sub[i][j];
    __syncthreads();
  }
#pragma unroll
  for (int i = 0; i < 4; ++i) {
    float4 v = make_float4(acc[i][0], acc[i][1], acc[i][2], acc[i][3]);
    *reinterpret_cast<float4*>(L + (size_t)(bm + tm + i) * NEXP + bn + tn) = v;
  }
}

// ---------------- Routing: one wave (64 lanes) per token ----------------
// lane l owns experts 4l..4l+3 (all in group l>>3; 8 lanes per group of 32 experts)
__global__ __launch_bounds__(256) void route_kernel(const float* __restrict__ L,
                                                    const float* __restrict__ bias,
                                                    int* __restrict__ sel_e,
                                                    float* __restrict__ sel_w) {
  const int gtid = blockIdx.x * blockDim.x + threadIdx.x;
  const int tok = gtid >> 6;
  const int lane = threadIdx.x & 63;
  const float4 lv = *reinterpret_cast<const float4*>(L + (size_t)tok * NEXP + lane * 4);
  const float4 bv = *reinterpret_cast<const float4*>(bias + lane * 4);
  float s[4];
  s[0] = (float)(1.0 / (1.0 + exp(-(double)lv.x))) + bv.x;
  s[1] = (float)(1.0 / (1.0 + exp(-(double)lv.y))) + bv.y;
  s[2] = (float)(1.0 / (1.0 + exp(-(double)lv.z))) + bv.z;
  s[3] = (float)(1.0 / (1.0 + exp(-(double)lv.w))) + bv.w;
  // top-2 of this lane's 4 scores (values only; sum is tie-insensitive)
  float hi01 = fmaxf(s[0], s[1]), lo01 = fminf(s[0], s[1]);
  float hi23 = fmaxf(s[2], s[3]), lo23 = fminf(s[2], s[3]);
  float m1 = fmaxf(hi01, hi23);
  float m2 = fmaxf(fminf(hi01, hi23), fmaxf(lo01, lo23));
  // merge top-2 pairs across the 8 lanes of the group
#pragma unroll
  for (int m = 1; m < 8; m <<= 1) {
    float o1 = __shfl_xor(m1, m);
    float o2 = __shfl_xor(m2, m);
    float n1 = fmaxf(m1, o1);
    float n2 = fmaxf(fminf(m1, o1), fmaxf(m2, o2));
    m1 = n1; m2 = n2;
  }
  const float gsum = m1 + m2;  // group score (same for all 8 lanes of the group)
  const int g = lane >> 3;
  // rank of my group among the 8 (jax top_k tie-break: lower index wins)
  int rank = 0;
#pragma unroll
  for (int j = 0; j < 8; ++j) {
    float gj = __shfl(gsum, j * 8);
    rank += (gj > gsum) || (gj == gsum && j < g);
  }
  const bool gsel = (rank < 4);
  float cand[4];
#pragma unroll
  for (int c = 0; c < 4; ++c) cand[c] = gsel ? s[c] : -INFINITY;
  // iterative top-8 over the 128 unmasked candidates
  float wv[8]; int we[8];
  float ssum = 0.f;
#pragma unroll
  for (int it = 0; it < 8; ++it) {
    float bvv = cand[0]; int bee = lane * 4;
#pragma unroll
    for (int c = 1; c < 4; ++c) {
      if (cand[c] > bvv) { bvv = cand[c]; bee = lane * 4 + c; }  // strict > keeps lower idx
    }
#pragma unroll
    for (int m = 1; m < 64; m <<= 1) {
      float ov = __shfl_xor(bvv, m);
      int oe = __shfl_xor(bee, m);
      if (ov > bvv || (ov == bvv && oe < bee)) { bvv = ov; bee = oe; }
    }
    wv[it] = bvv; we[it] = bee;
    ssum += bvv;
    if ((bee >> 2) == lane) cand[bee & 3] = -INFINITY;
  }
  const float scale = 2.5f / (ssum + 1e-20f);
  if (lane == 0) {
#pragma unroll
    for (int it = 0; it < 8; ++it) {
      sel_e[(size_t)tok * 8 + it] = we[it];
      sel_w[(size_t)tok * 8 + it] = wv[it] * scale;
    }
  }
}

// ---------------- Histogram ----------------
__global__ __launch_bounds__(256) void hist_kernel(const int* __restrict__ sel_e,
                                                   int* __restrict__ cnt) {
  int i = blockIdx.x * 256 + threadIdx.x;
  atomicAdd(&cnt[sel_e[i]], 1);
}

// ---------------- Stable scatter: one block per expert ----------------
__global__ __launch_bounds__(256) void scatter_kernel(const int* __restrict__ sel_e,
                                                      const float* __restrict__ sel_w,
                                                      const int* __restrict__ cnt,
                                                      float* __restrict__ out_scores,
                                                      float* __restrict__ out_tok,
                                                      float* __restrict__ out_cnt) {
  const int e = blockIdx.x;
  const int t = threadIdx.x;
  __shared__ int sc[NEXP];
  __shared__ int wcnt[4];
  sc[t] = cnt[t];
  __syncthreads();
  if (t == 0) out_cnt[e] = (float)sc[e];
  int base = 0;
  for (int j = 0; j < e; ++j) base += sc[j];  // exclusive prefix (LDS broadcast reads)
  int running = 0;
  for (int c = 0; c < (N_TOKENS * 8) / 256; ++c) {
    const int i = c * 256 + t;
    const bool match = (sel_e[i] == e);
    unsigned long long mb = __ballot(match);
    const int w = t >> 6, ln = t & 63;
    if (ln == 0) wcnt[w] = __popcll(mb);
    __syncthreads();
    int prefix = 0, tot = 0;
#pragma unroll
    for (int j = 0; j < 4; ++j) {
      int v = wcnt[j];
      tot += v;
      if (j < w) prefix += v;
    }
    if (match) {
      const int pos = base + running + prefix + __popcll(mb & ((1ull << ln) - 1));
      out_scores[pos] = sel_w[i];
      out_tok[pos] = (float)(i >> 3);  // token index = flat_idx / 8
    }
    running += tot;
    __syncthreads();
  }
}

extern "C" void kernel_launch(void* const* d_in, const int* in_sizes, int n_in,
                              void* d_out, int out_size, void* d_ws, size_t ws_size,
                              hipStream_t stream) {
  const float* x    = (const float*)d_in[0];
  const float* gw   = (const float*)d_in[1];
  const float* bias = (const float*)d_in[2];
  float* out = (float*)d_out;

  char* ws = (char*)d_ws;
  float* L     = (float*)ws;                                   // 8192*256*4 = 8 MiB
  size_t off   = (size_t)N_TOKENS * NEXP * sizeof(float);
  int*   sel_e = (int*)(ws + off);                             // 256 KiB
  float* sel_w = (float*)(ws + off + (size_t)N_TOKENS * 8 * 4);// 256 KiB
  int*   cnt   = (int*)(ws + off + 2 * (size_t)N_TOKENS * 8 * 4);

  hipMemsetAsync(cnt, 0, NEXP * sizeof(int), stream);

  dim3 gg(N_TOKENS / BM, NEXP / BN);
  gemm_f32<<<gg, 256, 0, stream>>>(x, gw, L);
  route_kernel<<<(N_TOKENS * 64) / 256, 256, 0, stream>>>(L, bias, sel_e, sel_w);
  hist_kernel<<<(N_TOKENS * 8) / 256, 256, 0, stream>>>(sel_e, cnt);
  scatter_kernel<<<NEXP, 256, 0, stream>>>(sel_e, sel_w, cnt,
                                           out, out + N_TOKENS * 8, out + 2 * N_TOKENS * 8);
}

// Round 3
// 732.705 us; speedup vs baseline: 1.3395x; 1.3395x over previous
//
#include <hip/hip_runtime.h>
#include <hip/hip_bf16.h>
#include <math.h>

#define N_TOKENS 8192
#define DIM 7168
#define NEXP 256
#define BM 128
#define BN 128
#define BK 64

typedef __attribute__((ext_vector_type(4))) float f32x4;
typedef __attribute__((ext_vector_type(8))) short short8;

__device__ __forceinline__ unsigned rne16(float v) {
  unsigned u = __builtin_bit_cast(unsigned, v);
  return u + 0x7FFFu + ((u >> 16) & 1u);   // high 16 bits = bf16 RNE of v
}
__device__ __forceinline__ float bf16hi_f32(unsigned t) {
  return __builtin_bit_cast(float, t & 0xFFFF0000u);
}

// ---- prep: split W (f32 [K][N]) into 3 bf16 planes, transposed [term][n][k] ----
__global__ __launch_bounds__(256) void prep_w(const float* __restrict__ W,
                                              unsigned short* __restrict__ wf) {
  int idx = blockIdx.x * 256 + threadIdx.x;
  int n = idx / (DIM / 8);
  int k0 = (idx % (DIM / 8)) * 8;
  short8 o1, o2, o3;
#pragma unroll
  for (int j = 0; j < 8; ++j) {
    float v = W[(size_t)(k0 + j) * NEXP + n];
    unsigned t1 = rne16(v);
    float r = v - bf16hi_f32(t1);
    unsigned t2 = rne16(r);
    float r2 = r - bf16hi_f32(t2);
    unsigned t3 = rne16(r2);
    o1[j] = (short)(t1 >> 16);
    o2[j] = (short)(t2 >> 16);
    o3[j] = (short)(t3 >> 16);
  }
  const size_t plane = (size_t)NEXP * DIM;
  size_t base = (size_t)n * DIM + k0;
  *(short8*)(wf + base) = o1;
  *(short8*)(wf + plane + base) = o2;
  *(short8*)(wf + 2 * plane + base) = o3;
}

// ---- GEMM: Lp[sk][8192][256] += X[m][k] * W[k][n] via 6-term bf16 MFMA ----
__global__ __launch_bounds__(256, 2) void gemm6(const float* __restrict__ X,
                                                const unsigned short* __restrict__ WF,
                                                float* __restrict__ Lp, int nsk) {
  __shared__ __align__(16) float xs[BM * BK];               // 32 KiB, swizzled
  __shared__ __align__(16) unsigned short wsb[3 * BN * BK]; // 48 KiB, swizzled
  const int bid = blockIdx.x;
  const int nb = bid & 1;
  const int sk = (bid >> 1) % nsk;
  const int mb = bid / (2 * nsk);
  const int bm = mb * BM, bn = nb * BN;
  const int kchunk = DIM / nsk;
  const int kbeg = sk * kchunk;
  const int t = threadIdx.x;
  const int wv = t >> 6, lane = t & 63;
  const int lm = lane & 15, lq = lane >> 4;

  f32x4 acc[2][8];
#pragma unroll
  for (int i = 0; i < 2; ++i)
#pragma unroll
    for (int j = 0; j < 8; ++j) acc[i][j] = (f32x4){0.f, 0.f, 0.f, 0.f};

  char* xsb = (char*)xs;
  char* wbb = (char*)wsb;

  for (int it = 0; it < kchunk / BK; ++it) {
    const int kb = kbeg + it * BK;
    // stage X tile (f32, [128 m][64 k], byte ^= ((m&7)<<4))
#pragma unroll
    for (int c = 0; c < 8; ++c) {
      int f = c * 1024 + t * 4;
      int row = f >> 6, kk = f & 63;
      f32x4 v = *(const f32x4*)(X + (size_t)(bm + row) * DIM + kb + kk);
      *(f32x4*)(xsb + row * 256 + ((kk * 4) ^ ((row & 7) << 4))) = v;
    }
    // stage W planes (bf16, [term][128 n][64 k], byte ^= ((n&7)<<4))
#pragma unroll
    for (int c = 0; c < 12; ++c) {
      int f = c * 256 + t;
      int term = f >> 10, r = f & 1023;
      int nloc = r >> 3, kc = (r & 7) << 4;
      short8 v = *(const short8*)((const char*)WF +
                  (((size_t)(term * NEXP + bn + nloc) * DIM + kb) << 1) + kc);
      *(short8*)(wbb + term * 16384 + nloc * 128 + (kc ^ ((nloc & 7) << 4))) = v;
    }
    __syncthreads();
#pragma unroll
    for (int ks = 0; ks < 2; ++ks) {
      short8 a1[2], a2[2], a3[2];
#pragma unroll
      for (int ms = 0; ms < 2; ++ms) {
        int mloc = (wv * 2 + ms) * 16 + lm;
        const char* pb = xsb + mloc * 256;
        int sw = (mloc & 7) << 4;
        int kbyte = ks * 128 + lq * 32;
        f32x4 lo = *(const f32x4*)(pb + (kbyte ^ sw));
        f32x4 hi = *(const f32x4*)(pb + ((kbyte + 16) ^ sw));
#pragma unroll
        for (int j = 0; j < 8; ++j) {
          float v = (j < 4) ? lo[j] : hi[j - 4];
          unsigned t1 = rne16(v);
          float r = v - bf16hi_f32(t1);
          unsigned t2 = rne16(r);
          float r2 = r - bf16hi_f32(t2);
          unsigned t3 = rne16(r2);
          a1[ms][j] = (short)(t1 >> 16);
          a2[ms][j] = (short)(t2 >> 16);
          a3[ms][j] = (short)(t3 >> 16);
        }
      }
#pragma unroll
      for (int ns = 0; ns < 8; ++ns) {
        int nloc = ns * 16 + lm;
        const char* pb = wbb + nloc * 128;
        int sw = (nloc & 7) << 4;
        int o = ((ks * 64 + lq * 16) ^ sw);
        short8 b1 = *(const short8*)(pb + o);
        short8 b2 = *(const short8*)(pb + 16384 + o);
        short8 b3 = *(const short8*)(pb + 32768 + o);
#pragma unroll
        for (int ms = 0; ms < 2; ++ms) {
          f32x4 c = acc[ms][ns];
          c = __builtin_amdgcn_mfma_f32_16x16x32_bf16(a1[ms], b1, c, 0, 0, 0);
          c = __builtin_amdgcn_mfma_f32_16x16x32_bf16(a1[ms], b2, c, 0, 0, 0);
          c = __builtin_amdgcn_mfma_f32_16x16x32_bf16(a2[ms], b1, c, 0, 0, 0);
          c = __builtin_amdgcn_mfma_f32_16x16x32_bf16(a1[ms], b3, c, 0, 0, 0);
          c = __builtin_amdgcn_mfma_f32_16x16x32_bf16(a2[ms], b2, c, 0, 0, 0);
          c = __builtin_amdgcn_mfma_f32_16x16x32_bf16(a3[ms], b1, c, 0, 0, 0);
          acc[ms][ns] = c;
        }
      }
    }
    __syncthreads();
  }
  float* out = Lp + (size_t)sk * N_TOKENS * NEXP;
#pragma unroll
  for (int ms = 0; ms < 2; ++ms) {
    int row0 = bm + (wv * 2 + ms) * 16 + lq * 4;
#pragma unroll
    for (int ns = 0; ns < 8; ++ns) {
      int col = bn + ns * 16 + lm;
#pragma unroll
      for (int r = 0; r < 4; ++r)
        out[(size_t)(row0 + r) * NEXP + col] = acc[ms][ns][r];
    }
  }
}

// ---------------- Routing: one wave per token; sums nsk partial slices ----------------
__global__ __launch_bounds__(256) void route_kernel(const float* __restrict__ Lp, int nsk,
                                                    const float* __restrict__ bias,
                                                    int* __restrict__ sel_e,
                                                    float* __restrict__ sel_w) {
  const int gtid = blockIdx.x * blockDim.x + threadIdx.x;
  const int tok = gtid >> 6;
  const int lane = threadIdx.x & 63;
  f32x4 lv = {0.f, 0.f, 0.f, 0.f};
  for (int s = 0; s < nsk; ++s)
    lv += *(const f32x4*)(Lp + ((size_t)s * N_TOKENS + tok) * NEXP + lane * 4);
  f32x4 bv = *(const f32x4*)(bias + lane * 4);
  float s[4];
#pragma unroll
  for (int c = 0; c < 4; ++c)
    s[c] = (float)(1.0 / (1.0 + exp(-(double)lv[c]))) + bv[c];
  // top-2 of this lane's 4 scores
  float hi01 = fmaxf(s[0], s[1]), lo01 = fminf(s[0], s[1]);
  float hi23 = fmaxf(s[2], s[3]), lo23 = fminf(s[2], s[3]);
  float m1 = fmaxf(hi01, hi23);
  float m2 = fmaxf(fminf(hi01, hi23), fmaxf(lo01, lo23));
#pragma unroll
  for (int m = 1; m < 8; m <<= 1) {
    float o1 = __shfl_xor(m1, m);
    float o2 = __shfl_xor(m2, m);
    float n1 = fmaxf(m1, o1);
    float n2 = fmaxf(fminf(m1, o1), fmaxf(m2, o2));
    m1 = n1; m2 = n2;
  }
  const float gsum = m1 + m2;
  const int g = lane >> 3;
  int rank = 0;
#pragma unroll
  for (int j = 0; j < 8; ++j) {
    float gj = __shfl(gsum, j * 8);
    rank += (gj > gsum) || (gj == gsum && j < g);
  }
  const bool gsel = (rank < 4);
  float cand[4];
#pragma unroll
  for (int c = 0; c < 4; ++c) cand[c] = gsel ? s[c] : -INFINITY;
  float wvv[8]; int we[8];
  float ssum = 0.f;
#pragma unroll
  for (int itr = 0; itr < 8; ++itr) {
    float bvv = cand[0]; int bee = lane * 4;
#pragma unroll
    for (int c = 1; c < 4; ++c)
      if (cand[c] > bvv) { bvv = cand[c]; bee = lane * 4 + c; }
#pragma unroll
    for (int m = 1; m < 64; m <<= 1) {
      float ov = __shfl_xor(bvv, m);
      int oe = __shfl_xor(bee, m);
      if (ov > bvv || (ov == bvv && oe < bee)) { bvv = ov; bee = oe; }
    }
    wvv[itr] = bvv; we[itr] = bee;
    ssum += bvv;
    if ((bee >> 2) == lane) cand[bee & 3] = -INFINITY;
  }
  const float scale = 2.5f / (ssum + 1e-20f);
  if (lane == 0) {
#pragma unroll
    for (int itr = 0; itr < 8; ++itr) {
      sel_e[(size_t)tok * 8 + itr] = we[itr];
      sel_w[(size_t)tok * 8 + itr] = wvv[itr] * scale;
    }
  }
}

// ---------------- Histogram ----------------
__global__ __launch_bounds__(256) void hist_kernel(const int* __restrict__ sel_e,
                                                   int* __restrict__ cnt) {
  int i = blockIdx.x * 256 + threadIdx.x;
  atomicAdd(&cnt[sel_e[i]], 1);
}

// ---------------- Stable scatter: 1 block per expert, 4 independent waves, 2-pass ----------------
__global__ __launch_bounds__(256) void scatter2(const int* __restrict__ sel_e,
                                                const float* __restrict__ sel_w,
                                                const int* __restrict__ cnt,
                                                float* __restrict__ out_s,
                                                float* __restrict__ out_t,
                                                float* __restrict__ out_c) {
  const int e = blockIdx.x;
  const int t = threadIdx.x, wv = t >> 6, lane = t & 63;
  __shared__ int wq[4];
  int pre = 0;
#pragma unroll
  for (int b = 0; b < 4; ++b) {
    int idx = b * 64 + lane;
    int v = cnt[idx];
    pre += (idx < e) ? v : 0;
  }
#pragma unroll
  for (int m = 1; m < 64; m <<= 1) pre += __shfl_xor(pre, m);
  if (t == 0) out_c[e] = (float)cnt[e];
  const int Q = (N_TOKENS * 8) / 4;
  const int start = wv * Q;
  int cw = 0;
#pragma unroll 8
  for (int c = 0; c < Q / 64; ++c)
    cw += (sel_e[start + c * 64 + lane] == e) ? 1 : 0;
#pragma unroll
  for (int m = 1; m < 64; m <<= 1) cw += __shfl_xor(cw, m);
  if (lane == 0) wq[wv] = cw;
  __syncthreads();
  int off = pre;
#pragma unroll
  for (int j = 0; j < 4; ++j) if (j < wv) off += wq[j];
  int run = 0;
  for (int c = 0; c < Q / 64; ++c) {
    int i = start + c * 64 + lane;
    bool mt = (sel_e[i] == e);
    unsigned long long mb = __ballot(mt);
    if (mt) {
      int pos = off + run + __popcll(mb & ((1ull << lane) - 1));
      out_s[pos] = sel_w[i];
      out_t[pos] = (float)(i >> 3);
    }
    run += __popcll(mb);
  }
}

extern "C" void kernel_launch(void* const* d_in, const int* in_sizes, int n_in,
                              void* d_out, int out_size, void* d_ws, size_t ws_size,
                              hipStream_t stream) {
  const float* x = (const float*)d_in[0];
  const float* gw = (const float*)d_in[1];
  const float* bias = (const float*)d_in[2];
  float* out = (float*)d_out;

  const size_t LBYTES = (size_t)N_TOKENS * NEXP * 4;   // 8 MiB per split-K slice
  const size_t WFB = (size_t)3 * NEXP * DIM * 2;       // 11.0 MB split-W planes
  const size_t SELB = (size_t)N_TOKENS * 8 * 4;        // 256 KiB

  int nsk = 1;
  if (4 * LBYTES + WFB + 2 * SELB + 1024 <= ws_size) nsk = 4;
  else if (2 * LBYTES + WFB + 2 * SELB + 1024 <= ws_size) nsk = 2;

  char* ws = (char*)d_ws;
  float* Lp = (float*)ws;
  unsigned short* wf = (unsigned short*)(ws + (size_t)nsk * LBYTES);
  int* sel_e = (int*)(ws + (size_t)nsk * LBYTES + WFB);
  float* sel_w = (float*)(ws + (size_t)nsk * LBYTES + WFB + SELB);
  int* cnt = (int*)(ws + (size_t)nsk * LBYTES + WFB + 2 * SELB);

  hipMemsetAsync(cnt, 0, NEXP * sizeof(int), stream);
  prep_w<<<(NEXP * (DIM / 8)) / 256, 256, 0, stream>>>(gw, wf);
  gemm6<<<(N_TOKENS / BM) * 2 * nsk, 256, 0, stream>>>(x, wf, Lp, nsk);
  route_kernel<<<(N_TOKENS * 64) / 256, 256, 0, stream>>>(Lp, nsk, bias, sel_e, sel_w);
  hist_kernel<<<(N_TOKENS * 8) / 256, 256, 0, stream>>>(sel_e, cnt);
  scatter2<<<NEXP, 256, 0, stream>>>(sel_e, sel_w, cnt,
                                     out, out + N_TOKENS * 8, out + 2 * N_TOKENS * 8);
}